// Round 1
// baseline (208.014 us; speedup 1.0000x reference)
//
#include <hip/hip_runtime.h>
#include <math.h>

// PrecisionFocusedLoss: mean over B of ce(logits, t) * (1 + 3*penalty)
//   penalty: FN (t==1, p==0) -> 1.0 ; FP (t==0, p==1) -> 5.0 ; else 0.1
//   => weight: FN -> 4.0 ; FP -> 16.0 ; else 1.3
// B = 8388608, C = 2. Memory-bound: 96 MiB in, 4 B out. Roofline ~16 us @ 6.3 TB/s.
//
// v2: - exact partition, fully unrolled: 4 quads/thread, 12 independent
//       dwordx4 loads in flight per thread (was: runtime-bounded grid-stride
//       loop, ~3 loads in flight, log1pf dependency chain between iterations)
//     - softplus via native v_exp_f32/v_log_f32 (__expf/__logf) instead of
//       libm log1pf (~30 insts + branches). Abs err ~1e-7/sample, averaged out.
//     - fused finalization: device-scope double atomicAdd + last-block-out.
//       Replaces the second kernel launch with a 16 B memset.

#define LOSS_BATCH 8388608
#define LOSS_GRID  2048
#define LOSS_BLOCK 256
#define LOSS_THREADS (LOSS_GRID * LOSS_BLOCK)          // 524288
#define QUADS_PER_THREAD 4                             // 524288*4 = 2097152 = B/4 exactly

__device__ __forceinline__ float sample_loss(float l0, float l1, int t) {
    // log-sum-exp over 2 classes, numerically stable:
    // lse = max + softplus(-|l0-l1|), softplus(x) = log(1+exp(x))
    float m  = fmaxf(l0, l1);
    float d  = fabsf(l0 - l1);
    float sp = __logf(1.0f + __expf(-d));   // native v_exp_f32 / v_log_f32
    float ce = (m + sp) - (t ? l1 : l0);
    // argmax with first-index tie-break: pred=1 iff l1 > l0
    bool p1 = l1 > l0;
    float w = 1.3f;                          // 1 + 3*0.1
    if (t) { if (!p1) w = 4.0f;  }           // false negative: 1 + 3*1.0
    else   { if (p1)  w = 16.0f; }           // false positive: 1 + 3*5.0
    return ce * w;
}

__global__ __launch_bounds__(LOSS_BLOCK) void loss_fused_kernel(
        const float4* __restrict__ logits4,   // 2 samples per float4
        const int4*   __restrict__ tgt4,      // 4 targets per int4
        double*       __restrict__ accum,     // ws+0  (memset to 0)
        unsigned int* __restrict__ count,     // ws+8  (memset to 0)
        float*        __restrict__ out)
{
    const int tid = blockIdx.x * LOSS_BLOCK + threadIdx.x;

    // Issue all 12 loads up front — independent, coalesced per instruction
    // (stride LOSS_THREADS keeps each load wave-contiguous).
    float4 a[QUADS_PER_THREAD], b[QUADS_PER_THREAD];
    int4   t[QUADS_PER_THREAD];
    #pragma unroll
    for (int k = 0; k < QUADS_PER_THREAD; ++k) {
        const int q = tid + k * LOSS_THREADS;
        a[k] = logits4[2 * q];       // samples 4q, 4q+1
        b[k] = logits4[2 * q + 1];   // samples 4q+2, 4q+3
        t[k] = tgt4[q];
    }

    float acc = 0.0f;
    #pragma unroll
    for (int k = 0; k < QUADS_PER_THREAD; ++k) {
        acc += sample_loss(a[k].x, a[k].y, t[k].x);
        acc += sample_loss(a[k].z, a[k].w, t[k].y);
        acc += sample_loss(b[k].x, b[k].y, t[k].z);
        acc += sample_loss(b[k].z, b[k].w, t[k].w);
    }

    // wave-64 reduction
    #pragma unroll
    for (int off = 32; off > 0; off >>= 1)
        acc += __shfl_down(acc, off, 64);
    __shared__ float smem[LOSS_BLOCK / 64];
    const int lane = threadIdx.x & 63;
    const int wid  = threadIdx.x >> 6;
    if (lane == 0) smem[wid] = acc;
    __syncthreads();

    if (threadIdx.x == 0) {
        const float s = smem[0] + smem[1] + smem[2] + smem[3];
        // device-scope coherent accumulation (double: ordering noise <= 1 ULP
        // of the final float)
        atomicAdd(accum, (double)s);
        __threadfence();                       // release: accum-add before count-add
        const unsigned int pos = atomicAdd(count, 1u);
        if (pos == LOSS_GRID - 1) {
            __threadfence();                   // acquire
            const double total = atomicAdd(accum, 0.0);  // coherent read of full sum
            out[0] = (float)(total / (double)LOSS_BATCH);
        }
    }
}

extern "C" void kernel_launch(void* const* d_in, const int* in_sizes, int n_in,
                              void* d_out, int out_size, void* d_ws, size_t ws_size,
                              hipStream_t stream) {
    const float4* logits4 = (const float4*)d_in[0];
    const int4*   tgt4    = (const int4*)d_in[1];
    double*       accum   = (double*)d_ws;
    unsigned int* count   = (unsigned int*)((char*)d_ws + 8);
    float*        out     = (float*)d_out;

    // workspace is poisoned between iterations — init the 16 B we use
    hipMemsetAsync(d_ws, 0, 16, stream);
    loss_fused_kernel<<<LOSS_GRID, LOSS_BLOCK, 0, stream>>>(
        logits4, tgt4, accum, count, out);
}

// Round 2
// 115.115 us; speedup vs baseline: 1.8070x; 1.8070x over previous
//
#include <hip/hip_runtime.h>
#include <math.h>

// PrecisionFocusedLoss: mean over B of ce(logits, t) * (1 + 3*penalty)
//   penalty: FN (t==1, p==0) -> 1.0 ; FP (t==0, p==1) -> 5.0 ; else 0.1
//   => weight: FN -> 4.0 ; FP -> 16.0 ; else 1.3
// B = 8388608, C = 2. Memory-bound: 96 MiB in, 4 B out.
//
// v3: v1's two-kernel finalization (per-block partials + tiny reduce; the
//     v2 single-address atomic tail serialized 2048 line-bounces ~90 us)
//     + v2's main-loop body:
//       - exact partition, fully unrolled: 4 quads/thread, 12 independent
//         dwordx4 loads issued up front (no runtime loop bound)
//       - softplus via native v_exp_f32/v_log_f32 (__expf/__logf), not libm
//         log1pf (slow path with branches)

#define LOSS_BATCH 8388608
#define LOSS_GRID  2048
#define LOSS_BLOCK 256
#define LOSS_THREADS (LOSS_GRID * LOSS_BLOCK)          // 524288
#define QUADS_PER_THREAD 4                             // 524288*4 = 2097152 = B/4 exactly

__device__ __forceinline__ float sample_loss(float l0, float l1, int t) {
    // log-sum-exp over 2 classes, numerically stable:
    // lse = max + softplus(-|l0-l1|), softplus(x) = log(1+exp(x))
    float m  = fmaxf(l0, l1);
    float d  = fabsf(l0 - l1);
    float sp = __logf(1.0f + __expf(-d));   // native v_exp_f32 / v_log_f32
    float ce = (m + sp) - (t ? l1 : l0);
    // argmax with first-index tie-break: pred=1 iff l1 > l0
    bool p1 = l1 > l0;
    float w = 1.3f;                          // 1 + 3*0.1
    if (t) { if (!p1) w = 4.0f;  }           // false negative: 1 + 3*1.0
    else   { if (p1)  w = 16.0f; }           // false positive: 1 + 3*5.0
    return ce * w;
}

__global__ __launch_bounds__(LOSS_BLOCK) void loss_partial_kernel(
        const float4* __restrict__ logits4,   // 2 samples per float4
        const int4*   __restrict__ tgt4,      // 4 targets per int4
        float*        __restrict__ partials)  // [LOSS_GRID]
{
    const int tid = blockIdx.x * LOSS_BLOCK + threadIdx.x;

    // Issue all 12 loads up front — independent, each instruction
    // wave-contiguous (stride LOSS_THREADS between iterations).
    float4 a[QUADS_PER_THREAD], b[QUADS_PER_THREAD];
    int4   t[QUADS_PER_THREAD];
    #pragma unroll
    for (int k = 0; k < QUADS_PER_THREAD; ++k) {
        const int q = tid + k * LOSS_THREADS;
        a[k] = logits4[2 * q];       // samples 4q, 4q+1
        b[k] = logits4[2 * q + 1];   // samples 4q+2, 4q+3
        t[k] = tgt4[q];
    }

    float acc = 0.0f;
    #pragma unroll
    for (int k = 0; k < QUADS_PER_THREAD; ++k) {
        acc += sample_loss(a[k].x, a[k].y, t[k].x);
        acc += sample_loss(a[k].z, a[k].w, t[k].y);
        acc += sample_loss(b[k].x, b[k].y, t[k].z);
        acc += sample_loss(b[k].z, b[k].w, t[k].w);
    }

    // wave-64 reduction
    #pragma unroll
    for (int off = 32; off > 0; off >>= 1)
        acc += __shfl_down(acc, off, 64);
    __shared__ float smem[LOSS_BLOCK / 64];
    const int lane = threadIdx.x & 63;
    const int wid  = threadIdx.x >> 6;
    if (lane == 0) smem[wid] = acc;
    __syncthreads();
    if (threadIdx.x == 0)
        partials[blockIdx.x] = smem[0] + smem[1] + smem[2] + smem[3];
}

__global__ __launch_bounds__(256) void loss_final_kernel(
        const float* __restrict__ partials, float* __restrict__ out)
{
    double acc = 0.0;
    #pragma unroll
    for (int i = 0; i < LOSS_GRID / 256; ++i)
        acc += (double)partials[threadIdx.x + i * 256];
    #pragma unroll
    for (int off = 32; off > 0; off >>= 1)
        acc += __shfl_down(acc, off, 64);
    __shared__ double smem[4];
    const int lane = threadIdx.x & 63;
    const int wid  = threadIdx.x >> 6;
    if (lane == 0) smem[wid] = acc;
    __syncthreads();
    if (threadIdx.x == 0) {
        double s = smem[0] + smem[1] + smem[2] + smem[3];
        out[0] = (float)(s / (double)LOSS_BATCH);
    }
}

extern "C" void kernel_launch(void* const* d_in, const int* in_sizes, int n_in,
                              void* d_out, int out_size, void* d_ws, size_t ws_size,
                              hipStream_t stream) {
    const float4* logits4 = (const float4*)d_in[0];
    const int4*   tgt4    = (const int4*)d_in[1];
    float* partials = (float*)d_ws;           // LOSS_GRID floats = 8 KB
    float* out      = (float*)d_out;

    loss_partial_kernel<<<LOSS_GRID, LOSS_BLOCK, 0, stream>>>(logits4, tgt4, partials);
    loss_final_kernel<<<1, 256, 0, stream>>>(partials, out);
}